// Round 9
// baseline (162.939 us; speedup 1.0000x reference)
//
#include <hip/hip_runtime.h>

#define Nn 4096
#define FIN 512
#define NH 8
#define O1 512
#define LOG2E 1.44269504088896f

typedef __attribute__((ext_vector_type(8))) short short8;
typedef __attribute__((ext_vector_type(4))) float f32x4;
typedef __attribute__((ext_vector_type(2))) unsigned int u32x2;

__device__ __forceinline__ unsigned short f2bf(float f){
  union{float f; unsigned u;} x; x.f=f;
  unsigned r = x.u + 0x7fffu + ((x.u>>16)&1u);
  return (unsigned short)(r>>16);
}
__device__ __forceinline__ float bf2f(unsigned short b){
  union{unsigned u; float f;} x; x.u=((unsigned)b)<<16;
  return x.f;
}
__device__ __forceinline__ unsigned cvtpk_bf16(float a, float b){
  unsigned r; asm("v_cvt_pk_bf16_f32 %0, %1, %2" : "=v"(r) : "v"(a), "v"(b));
  return r;
}
// async 16B global -> LDS (per-lane global src, wave-uniform LDS base + lane*16)
__device__ __forceinline__ void gload_lds16(const unsigned short* g, unsigned short* l){
  __builtin_amdgcn_global_load_lds(
      (const __attribute__((address_space(1))) unsigned int*)g,
      (__attribute__((address_space(3))) unsigned int*)l, 16, 0, 0);
}

// ---- pack adjacency int32 -> bitmask ----
__global__ void k_pack_adj(const int* __restrict__ adj, unsigned long long* __restrict__ adjw){
  size_t tid = (size_t)blockIdx.x*blockDim.x + threadIdx.x;
  int v = __builtin_nontemporal_load(adj + tid);   // 64MB read-once
  unsigned long long m = __ballot(v>0);
  if((threadIdx.x&63)==0) adjw[tid>>6] = m;
}

// ---- f32 -> bf16 convert ----
__global__ void k_cvt(const float* __restrict__ in, unsigned short* __restrict__ out, int n){
  int i = (blockIdx.x*blockDim.x + threadIdx.x)*4;
  if(i>=n) return;
  float4 v = *(const float4*)(in+i);
  u32x2 pk; pk.x = cvtpk_bf16(v.x, v.y); pk.y = cvtpk_bf16(v.z, v.w);
  *(u32x2*)(out+i) = pk;
}

// ---- K-split GEMM: C^T[o][m] = sum_k A[m][k]*B[o][k] ----
template<int NWC, int KS>
__global__ __launch_bounds__(NWC*KS*64, 2)
void k_gemm3(const unsigned short* __restrict__ A, const unsigned short* __restrict__ B,
             unsigned short* __restrict__ CT, int M, int K, int O){
  int t=threadIdx.x, l=t&63, w=t>>6;
  int wc=w%NWC, ks=w/NWC;
  int m0=blockIdx.x*32, o0=blockIdx.y*(NWC*32);
  int row=l&15, kq=(l>>4)*8, g=l>>4;
  int kw=K/KS;
  const unsigned short* Ab = A + (size_t)(m0+row)*K + ks*kw + kq;
  const unsigned short* Bb = B + (size_t)(o0+wc*32+row)*K + ks*kw + kq;
  f32x4 acc[2][2]={};
  #pragma unroll 2
  for(int k0=0;k0<kw;k0+=32){
    short8 a0=*(const short8*)(Ab+k0);
    short8 a1=*(const short8*)(Ab+(size_t)16*K+k0);
    short8 b0=*(const short8*)(Bb+k0);
    short8 b1=*(const short8*)(Bb+(size_t)16*K+k0);
    acc[0][0]=__builtin_amdgcn_mfma_f32_16x16x32_bf16(a0,b0,acc[0][0],0,0,0);
    acc[0][1]=__builtin_amdgcn_mfma_f32_16x16x32_bf16(a0,b1,acc[0][1],0,0,0);
    acc[1][0]=__builtin_amdgcn_mfma_f32_16x16x32_bf16(a1,b0,acc[1][0],0,0,0);
    acc[1][1]=__builtin_amdgcn_mfma_f32_16x16x32_bf16(a1,b1,acc[1][1],0,0,0);
  }
  __shared__ float red[NWC][KS/2][32][36];
  for(int s=KS/2;s>=1;s>>=1){
    if(ks>=s && ks<2*s){
      #pragma unroll
      for(int mi=0;mi<2;mi++)
      #pragma unroll
      for(int oi=0;oi<2;oi++)
      #pragma unroll
      for(int r=0;r<4;r++)
        red[wc][ks-s][mi*16+g*4+r][oi*18+row]=acc[mi][oi][r];
    }
    __syncthreads();
    if(ks<s){
      #pragma unroll
      for(int mi=0;mi<2;mi++)
      #pragma unroll
      for(int oi=0;oi<2;oi++)
      #pragma unroll
      for(int r=0;r<4;r++)
        acc[mi][oi][r]+=red[wc][ks][mi*16+g*4+r][oi*18+row];
    }
    __syncthreads();
  }
  if(ks==0){
    #pragma unroll
    for(int mi=0;mi<2;mi++)
    #pragma unroll
    for(int oi=0;oi<2;oi++){
      int m=m0+mi*16+g*4;
      int o=o0+wc*32+oi*16+row;
      u32x2 pk;
      pk.x=cvtpk_bf16(acc[mi][oi][0], acc[mi][oi][1]);
      pk.y=cvtpk_bf16(acc[mi][oi][2], acc[mi][oi][3]);
      *(u32x2*)&CT[(size_t)o*M+m] = pk;
    }
  }
}

// ---- per-node score factors: E=2^(s*log2e), F=2^(0.2*s*log2e) ----
__global__ void k_wh12(const unsigned short* __restrict__ whT,
                       const float* __restrict__ a1, const float* __restrict__ a2,
                       float2* __restrict__ e1f1, float2* __restrict__ e2f2){
  const int M=Nn;
  int n=blockIdx.x*blockDim.x+threadIdx.x;
  int h=blockIdx.y;
  float s1=0.f,s2=0.f;
  for(int c=0;c<64;c++){
    float v=bf2f(whT[(size_t)(h*64+c)*M+n]);
    s1+=v*a1[h*64+c];
    s2+=v*a2[h*64+c];
  }
  float s1L=s1*LOG2E, s2L=s2*LOG2E;
  float2 r1; r1.x=__builtin_amdgcn_exp2f(s1L); r1.y=__builtin_amdgcn_exp2f(0.2f*s1L);
  float2 r2; r2.x=__builtin_amdgcn_exp2f(s2L); r2.y=__builtin_amdgcn_exp2f(0.2f*s2L);
  e1f1[(size_t)h*M+n]=r1;
  e2f2[(size_t)h*M+n]=r2;
}

// ---- fused attention: async gload_lds V staging, XOR-swizzled LDS, 2-phase pipeline ----
// Block: 4 waves x 16 rows. V tile [64 c][64 j] double-buffered (16KB), swizzle:
// 16B-group c8 of row r stored at c8^(r&7) (linear 128B rows, conflict-free).
// Stage via per-lane pre-swizzled global src. One __syncthreads per step
// (its vmcnt drain is the stage fence). e2f2/adjw prefetched one step ahead.
template<int FINAL, int JSTEPS, int LOGH>
__global__ __launch_bounds__(256, 2)
void k_attn6(const unsigned long long* __restrict__ adjw,
             const float2* __restrict__ e1f1, const float2* __restrict__ e2f2,
             const unsigned short* __restrict__ whT,
             unsigned short* __restrict__ Hmat,
             float* __restrict__ Opart, float* __restrict__ Dpart){
  const int M = Nn;
  __shared__ unsigned short buf[2][64][64];
  int t = threadIdx.x, l = t & 63, w = t >> 6;
  int lr = l & 15, g = l >> 4;
  int bid = blockIdx.x;
  int h = bid & ((1<<LOGH)-1);
  int bx = bid >> LOGH;
  int rowtile, jc;
  if (FINAL) { jc = bx & 7; rowtile = bx >> 3; }
  else       { jc = 0;      rowtile = bx; }
  int i_base = rowtile*64;
  int jbase = jc * (JSTEPS*64);
  const float2* ef2h = e2f2 + (size_t)h*M;
  const unsigned short* Vb = whT + (size_t)h*64*M;
  int i = i_base + w*16 + lr;
  float2 ef = e1f1[(size_t)h*M + i];
  float E1 = ef.x, F1 = ef.y;
  const unsigned long long* arow = adjw + (size_t)i*64;

  // staging source (pre-swizzled): instr k, lane l -> phys row w*16+k*8+l/8,
  // phys group l&7 holds logical group (l&7)^(row&7)
  int rloc0 = w*16 + (l>>3);
  int rloc1 = rloc0 + 8;
  const unsigned short* vsrc0 = Vb + (size_t)rloc0*M + jbase + (((l&7)^(rloc0&7))<<3);
  const unsigned short* vsrc1 = Vb + (size_t)rloc1*M + jbase + (((l&7)^(rloc1&7))<<3);

  short8 ones;
  #pragma unroll
  for (int q=0;q<8;q++) ones[q] = (short)0x3F80;

  f32x4 acc[4] = {};
  f32x4 accd = {};

  #define STAGE(nb, s) do{ \
      gload_lds16(vsrc0 + (size_t)(s)*64, &buf[nb][w*16][0]);   \
      gload_lds16(vsrc1 + (size_t)(s)*64, &buf[nb][w*16+8][0]); \
    }while(0)

  // prologue: stage step 0, prefetch step-0 scalars
  STAGE(0, 0);
  float4 cc[8];
  #pragma unroll
  for (int half=0; half<2; half++){
    const float2* efp = ef2h + jbase + half*32 + g*8;
    #pragma unroll
    for (int k=0;k<4;k++) cc[half*4+k] = *(const float4*)(efp + 2*k);
  }
  unsigned long long wrd = arow[jbase>>6];
  __syncthreads();   // drains stage(0) on all waves

  for (int s = 0; s < JSTEPS; s++){
    if (s+1 < JSTEPS) STAGE((s+1)&1, s+1);     // async, lands during compute
    // ---- P compute from prefetched regs ----
    unsigned pu[2][4];
    #pragma unroll
    for (int half = 0; half < 2; half++){
      float Ee[8] = {cc[half*4+0].x,cc[half*4+0].z,cc[half*4+1].x,cc[half*4+1].z,
                     cc[half*4+2].x,cc[half*4+2].z,cc[half*4+3].x,cc[half*4+3].z};
      float Ff[8] = {cc[half*4+0].y,cc[half*4+0].w,cc[half*4+1].y,cc[half*4+1].w,
                     cc[half*4+2].y,cc[half*4+2].w,cc[half*4+3].y,cc[half*4+3].w};
      unsigned bits = (unsigned)(wrd >> (half*32 + g*8)) & 0xffu;
      float pf[8];
      #pragma unroll
      for (int q = 0; q < 8; q++){
        float m = E1*Ee[q];
        float f = F1*Ff[q];
        float p = fmaxf(m, f);                 // = exp2(LeakyReLU(s))
        int mk = (int)(bits << (31-q)) >> 31;
        pf[q] = __uint_as_float(__float_as_uint(p) & (unsigned)mk);
      }
      #pragma unroll
      for (int k = 0; k < 4; k++) pu[half][k] = cvtpk_bf16(pf[2*k], pf[2*k+1]);
    }
    // ---- prefetch next-step scalars (in flight during MFMA) ----
    if (s+1 < JSTEPS){
      int jn = jbase + (s+1)*64;
      #pragma unroll
      for (int half=0; half<2; half++){
        const float2* efp = ef2h + jn + half*32 + g*8;
        #pragma unroll
        for (int k=0;k<4;k++) cc[half*4+k] = *(const float4*)(efp + 2*k);
      }
      wrd = arow[jn>>6];
    }
    // ---- MFMA phase: swizzled ds_reads (conflict-free) ----
    #pragma unroll
    for (int half = 0; half < 2; half++){
      union { unsigned u[4]; short8 v; } pv_;
      #pragma unroll
      for (int k = 0; k < 4; k++) pv_.u[k] = pu[half][k];
      #pragma unroll
      for (int ct = 0; ct < 4; ct++){
        int r = ct*16 + lr;
        short8 bfr = *(const short8*)&buf[s&1][r][(((half*4+g)^(lr&7))<<3)];
        acc[ct] = __builtin_amdgcn_mfma_f32_16x16x32_bf16(pv_.v, bfr, acc[ct], 0,0,0);
      }
      accd = __builtin_amdgcn_mfma_f32_16x16x32_bf16(pv_.v, ones, accd, 0,0,0);
    }
    __syncthreads();   // vmcnt drain = stage fence; also protects buf reuse
  }
  #undef STAGE

  // ---- epilogue (per-wave) ----
  if (FINAL){
    #pragma unroll
    for (int r=0; r<4; r++){
      int row = i_base + w*16 + g*4 + r;
      if (lr == 0) Dpart[(size_t)jc*Nn + row] = accd[r];
      #pragma unroll
      for (int ct=0; ct<4; ct++)
        Opart[((size_t)jc*Nn + row)*64 + ct*16 + lr] = acc[ct][r];
    }
  } else {
    #pragma unroll
    for (int r=0; r<4; r++){
      float d  = fmaxf(accd[r], 1e-30f);
      float rd = 1.f/d;
      int row = i_base + w*16 + g*4 + r;
      #pragma unroll
      for (int ct=0; ct<4; ct++){
        float v = acc[ct][r]*rd;
        v = v > 0.f ? v : __expf(v) - 1.f;   // ELU
        Hmat[(size_t)row*O1 + h*64 + ct*16 + lr] = f2bf(v);
      }
    }
  }
}

// ---- layer-2 finish: combine 8 j-chunk partials, normalize, ELU, log_softmax ----
__global__ void k_fin(const float* __restrict__ Op, const float* __restrict__ Dp,
                      float* __restrict__ out){
  int w = threadIdx.x>>6, l = threadIdx.x&63;
  int row = blockIdx.x*4 + w;
  float o = 0.f, d = 0.f;
  #pragma unroll
  for (int jc=0; jc<8; jc++){
    o += Op[((size_t)jc*Nn + row)*64 + l];
    d += Dp[(size_t)jc*Nn + row];
  }
  float v = o / fmaxf(d, 1e-30f);
  v = v > 0.f ? v : __expf(v) - 1.f;
  float m = v;
  #pragma unroll
  for (int dd=1; dd<64; dd<<=1) m = fmaxf(m, __shfl_xor(m, dd));
  float s = __expf(v - m);
  #pragma unroll
  for (int dd=1; dd<64; dd<<=1) s += __shfl_xor(s, dd);
  out[(size_t)row*64 + l] = v - (m + __logf(s));
}

extern "C" void kernel_launch(void* const* d_in, const int* in_sizes, int n_in,
                              void* d_out, int out_size, void* d_ws, size_t ws_size,
                              hipStream_t stream){
  const float* x  = (const float*)d_in[0];
  const int* adj  = (const int*)d_in[1];
  const float* W  = (const float*)d_in[2];
  const float* a1 = (const float*)d_in[3];
  const float* a2 = (const float*)d_in[4];
  const float* W2 = (const float*)d_in[5];
  const float* a21= (const float*)d_in[6];
  const float* a22= (const float*)d_in[7];
  float* out = (float*)d_out;
  char* ws = (char*)d_ws;

  size_t off=0;
  unsigned long long* adjw = (unsigned long long*)(ws+off); off += (size_t)Nn*64*8;   // 2MB
  size_t off_xb = off;
  unsigned short* xb   = (unsigned short*)(ws+off); off += (size_t)Nn*FIN*2;          // 4MB
  unsigned short* Wb   = (unsigned short*)(ws+off); off += (size_t)O1*FIN*2;          // .5MB
  unsigned short* W2b  = (unsigned short*)(ws+off); off += (size_t)64*FIN*2;          // 64KB
  unsigned short* whT1 = (unsigned short*)(ws+off); off += (size_t)O1*Nn*2;           // 4MB
  unsigned short* Hmat = (unsigned short*)(ws+off); off += (size_t)Nn*O1*2;           // 4MB
  unsigned short* whT2 = (unsigned short*)(ws+off); off += (size_t)64*Nn*2;           // .5MB
  float2* e1f1a = (float2*)(ws+off); off += (size_t)NH*Nn*8;
  float2* e2f2a = (float2*)(ws+off); off += (size_t)NH*Nn*8;
  float2* e1f1b = (float2*)(ws+off); off += (size_t)Nn*8;
  float2* e2f2b = (float2*)(ws+off); off += (size_t)Nn*8;
  // layer-2 partials alias the dead xb/Wb/W2b/whT1 region
  float* Opart = (float*)(ws + off_xb);                     // 8MB
  float* Dpart = (float*)(ws + off_xb + (size_t)8*Nn*64*4); // 128KB

  k_pack_adj<<<(Nn*(size_t)Nn)/256, 256, 0, stream>>>(adj, adjw);
  k_cvt<<<(Nn*FIN/4+255)/256, 256, 0, stream>>>(x, xb, Nn*FIN);
  k_cvt<<<(O1*FIN/4+255)/256, 256, 0, stream>>>(W, Wb, O1*FIN);
  k_cvt<<<(64*FIN/4+255)/256, 256, 0, stream>>>(W2, W2b, 64*FIN);
  k_gemm3<2,4><<<dim3(Nn/32, O1/64), 512, 0, stream>>>(xb, Wb, whT1, Nn, FIN, O1);
  k_wh12<<<dim3(Nn/256, NH), 256, 0, stream>>>(whT1, a1, a2, e1f1a, e2f2a);
  // layer-1 attention: 64 rowtiles x 8 heads, full-j sweep
  k_attn6<0, 64, 3><<<(Nn/64)*NH, 256, 0, stream>>>(adjw, e1f1a, e2f2a, whT1, Hmat, nullptr, nullptr);
  k_gemm3<2,8><<<dim3(Nn/32, 1), 1024, 0, stream>>>(Hmat, W2b, whT2, Nn, FIN, 64);
  k_wh12<<<dim3(Nn/256, 1), 256, 0, stream>>>(whT2, a21, a22, e1f1b, e2f2b);
  // layer-2 attention: 64 rowtiles x 8 j-chunks -> partials
  k_attn6<1, 8, 0><<<(Nn/64)*8, 256, 0, stream>>>(adjw, e1f1b, e2f2b, whT2, nullptr, Opart, Dpart);
  k_fin<<<Nn/4, 256, 0, stream>>>(Opart, Dpart, out);
  (void)in_sizes; (void)n_in; (void)out_size; (void)ws_size;
}

// Round 10
// 158.064 us; speedup vs baseline: 1.0308x; 1.0308x over previous
//
#include <hip/hip_runtime.h>

#define Nn 4096
#define FIN 512
#define NH 8
#define O1 512
#define LOG2E 1.44269504088896f

typedef __attribute__((ext_vector_type(8))) short short8;
typedef __attribute__((ext_vector_type(4))) float f32x4;
typedef __attribute__((ext_vector_type(2))) unsigned int u32x2;

__device__ __forceinline__ unsigned short f2bf(float f){
  union{float f; unsigned u;} x; x.f=f;
  unsigned r = x.u + 0x7fffu + ((x.u>>16)&1u);
  return (unsigned short)(r>>16);
}
__device__ __forceinline__ float bf2f(unsigned short b){
  union{unsigned u; float f;} x; x.u=((unsigned)b)<<16;
  return x.f;
}
__device__ __forceinline__ unsigned cvtpk_bf16(float a, float b){
  unsigned r; asm("v_cvt_pk_bf16_f32 %0, %1, %2" : "=v"(r) : "v"(a), "v"(b));
  return r;
}
// async 16B global -> LDS (per-lane global src, wave-uniform LDS base + lane*16)
__device__ __forceinline__ void gload_lds16(const unsigned short* g, unsigned short* l){
  __builtin_amdgcn_global_load_lds(
      (const __attribute__((address_space(1))) unsigned int*)g,
      (__attribute__((address_space(3))) unsigned int*)l, 16, 0, 0);
}

// ---- pack adjacency int32 -> bitmask ----
__global__ void k_pack_adj(const int* __restrict__ adj, unsigned long long* __restrict__ adjw){
  size_t tid = (size_t)blockIdx.x*blockDim.x + threadIdx.x;
  int v = __builtin_nontemporal_load(adj + tid);   // 64MB read-once
  unsigned long long m = __ballot(v>0);
  if((threadIdx.x&63)==0) adjw[tid>>6] = m;
}

// ---- f32 -> bf16 convert ----
__global__ void k_cvt(const float* __restrict__ in, unsigned short* __restrict__ out, int n){
  int i = (blockIdx.x*blockDim.x + threadIdx.x)*4;
  if(i>=n) return;
  float4 v = *(const float4*)(in+i);
  u32x2 pk; pk.x = cvtpk_bf16(v.x, v.y); pk.y = cvtpk_bf16(v.z, v.w);
  *(u32x2*)(out+i) = pk;
}

// ---- K-split GEMM: C^T[o][m] = sum_k A[m][k]*B[o][k] ----
template<int NWC, int KS>
__global__ __launch_bounds__(NWC*KS*64, 2)
void k_gemm3(const unsigned short* __restrict__ A, const unsigned short* __restrict__ B,
             unsigned short* __restrict__ CT, int M, int K, int O){
  int t=threadIdx.x, l=t&63, w=t>>6;
  int wc=w%NWC, ks=w/NWC;
  int m0=blockIdx.x*32, o0=blockIdx.y*(NWC*32);
  int row=l&15, kq=(l>>4)*8, g=l>>4;
  int kw=K/KS;
  const unsigned short* Ab = A + (size_t)(m0+row)*K + ks*kw + kq;
  const unsigned short* Bb = B + (size_t)(o0+wc*32+row)*K + ks*kw + kq;
  f32x4 acc[2][2]={};
  #pragma unroll 2
  for(int k0=0;k0<kw;k0+=32){
    short8 a0=*(const short8*)(Ab+k0);
    short8 a1=*(const short8*)(Ab+(size_t)16*K+k0);
    short8 b0=*(const short8*)(Bb+k0);
    short8 b1=*(const short8*)(Bb+(size_t)16*K+k0);
    acc[0][0]=__builtin_amdgcn_mfma_f32_16x16x32_bf16(a0,b0,acc[0][0],0,0,0);
    acc[0][1]=__builtin_amdgcn_mfma_f32_16x16x32_bf16(a0,b1,acc[0][1],0,0,0);
    acc[1][0]=__builtin_amdgcn_mfma_f32_16x16x32_bf16(a1,b0,acc[1][0],0,0,0);
    acc[1][1]=__builtin_amdgcn_mfma_f32_16x16x32_bf16(a1,b1,acc[1][1],0,0,0);
  }
  __shared__ float red[NWC][KS/2][32][36];
  for(int s=KS/2;s>=1;s>>=1){
    if(ks>=s && ks<2*s){
      #pragma unroll
      for(int mi=0;mi<2;mi++)
      #pragma unroll
      for(int oi=0;oi<2;oi++)
      #pragma unroll
      for(int r=0;r<4;r++)
        red[wc][ks-s][mi*16+g*4+r][oi*18+row]=acc[mi][oi][r];
    }
    __syncthreads();
    if(ks<s){
      #pragma unroll
      for(int mi=0;mi<2;mi++)
      #pragma unroll
      for(int oi=0;oi<2;oi++)
      #pragma unroll
      for(int r=0;r<4;r++)
        acc[mi][oi][r]+=red[wc][ks][mi*16+g*4+r][oi*18+row];
    }
    __syncthreads();
  }
  if(ks==0){
    #pragma unroll
    for(int mi=0;mi<2;mi++)
    #pragma unroll
    for(int oi=0;oi<2;oi++){
      int m=m0+mi*16+g*4;
      int o=o0+wc*32+oi*16+row;
      u32x2 pk;
      pk.x=cvtpk_bf16(acc[mi][oi][0], acc[mi][oi][1]);
      pk.y=cvtpk_bf16(acc[mi][oi][2], acc[mi][oi][3]);
      *(u32x2*)&CT[(size_t)o*M+m] = pk;
    }
  }
}

// ---- per-node score factors: E=2^(s*log2e), F=2^(0.2*s*log2e) ----
__global__ void k_wh12(const unsigned short* __restrict__ whT,
                       const float* __restrict__ a1, const float* __restrict__ a2,
                       float2* __restrict__ e1f1, float2* __restrict__ e2f2){
  const int M=Nn;
  int n=blockIdx.x*blockDim.x+threadIdx.x;
  int h=blockIdx.y;
  float s1=0.f,s2=0.f;
  for(int c=0;c<64;c++){
    float v=bf2f(whT[(size_t)(h*64+c)*M+n]);
    s1+=v*a1[h*64+c];
    s2+=v*a2[h*64+c];
  }
  float s1L=s1*LOG2E, s2L=s2*LOG2E;
  float2 r1; r1.x=__builtin_amdgcn_exp2f(s1L); r1.y=__builtin_amdgcn_exp2f(0.2f*s1L);
  float2 r2; r2.x=__builtin_amdgcn_exp2f(s2L); r2.y=__builtin_amdgcn_exp2f(0.2f*s2L);
  e1f1[(size_t)h*M+n]=r1;
  e2f2[(size_t)h*M+n]=r2;
}

// ---- fused attention: async gload_lds V, XOR-swizzled LDS, 2-phase pipeline,
// j-chunked for occupancy. Block: 4 waves x 16 rows. Writes bf16 O-partials +
// fp32 D-partials indexed by (h<<JCLOG | jc). ----
template<int JSTEPS, int LOGH, int JCLOG>
__global__ __launch_bounds__(256, 4)
void k_attn6(const unsigned long long* __restrict__ adjw,
             const float2* __restrict__ e1f1, const float2* __restrict__ e2f2,
             const unsigned short* __restrict__ whT,
             unsigned short* __restrict__ Opart, float* __restrict__ Dpart){
  const int M = Nn;
  __shared__ unsigned short buf[2][64][64];
  int t = threadIdx.x, l = t & 63, w = t >> 6;
  int lr = l & 15, g = l >> 4;
  int bid = blockIdx.x;
  int h = bid & ((1<<LOGH)-1);          // head in low bits -> pinned per XCD
  int bx = bid >> LOGH;
  int jc = bx & ((1<<JCLOG)-1);
  int rowtile = bx >> JCLOG;
  int i_base = rowtile*64;
  int jbase = jc * (JSTEPS*64);
  const float2* ef2h = e2f2 + (size_t)h*M;
  const unsigned short* Vb = whT + (size_t)h*64*M;
  int i = i_base + w*16 + lr;
  float2 ef = e1f1[(size_t)h*M + i];
  float E1 = ef.x, F1 = ef.y;
  const unsigned long long* arow = adjw + (size_t)i*64;

  // pre-swizzled staging source: phys group l&7 holds logical group (l&7)^(row&7)
  int rloc0 = w*16 + (l>>3);
  int rloc1 = rloc0 + 8;
  const unsigned short* vsrc0 = Vb + (size_t)rloc0*M + jbase + (((l&7)^(rloc0&7))<<3);
  const unsigned short* vsrc1 = Vb + (size_t)rloc1*M + jbase + (((l&7)^(rloc1&7))<<3);

  short8 ones;
  #pragma unroll
  for (int q=0;q<8;q++) ones[q] = (short)0x3F80;

  f32x4 acc[4] = {};
  f32x4 accd = {};

  #define STAGE(nb, s) do{ \
      gload_lds16(vsrc0 + (size_t)(s)*64, &buf[nb][w*16][0]);   \
      gload_lds16(vsrc1 + (size_t)(s)*64, &buf[nb][w*16+8][0]); \
    }while(0)

  STAGE(0, 0);
  float4 cc[8];
  #pragma unroll
  for (int half=0; half<2; half++){
    const float2* efp = ef2h + jbase + half*32 + g*8;
    #pragma unroll
    for (int k=0;k<4;k++) cc[half*4+k] = *(const float4*)(efp + 2*k);
  }
  unsigned long long wrd = arow[jbase>>6];
  __syncthreads();   // drains stage(0)

  for (int s = 0; s < JSTEPS; s++){
    if (s+1 < JSTEPS) STAGE((s+1)&1, s+1);   // async, lands during compute
    unsigned pu[2][4];
    #pragma unroll
    for (int half = 0; half < 2; half++){
      float Ee[8] = {cc[half*4+0].x,cc[half*4+0].z,cc[half*4+1].x,cc[half*4+1].z,
                     cc[half*4+2].x,cc[half*4+2].z,cc[half*4+3].x,cc[half*4+3].z};
      float Ff[8] = {cc[half*4+0].y,cc[half*4+0].w,cc[half*4+1].y,cc[half*4+1].w,
                     cc[half*4+2].y,cc[half*4+2].w,cc[half*4+3].y,cc[half*4+3].w};
      unsigned bits = (unsigned)(wrd >> (half*32 + g*8)) & 0xffu;
      float pf[8];
      #pragma unroll
      for (int q = 0; q < 8; q++){
        float m = E1*Ee[q];
        float f = F1*Ff[q];
        float p = fmaxf(m, f);                 // = exp2(LeakyReLU(s))
        int mk = (int)(bits << (31-q)) >> 31;
        pf[q] = __uint_as_float(__float_as_uint(p) & (unsigned)mk);
      }
      #pragma unroll
      for (int k = 0; k < 4; k++) pu[half][k] = cvtpk_bf16(pf[2*k], pf[2*k+1]);
    }
    if (s+1 < JSTEPS){                        // prefetch next-step scalars
      int jn = jbase + (s+1)*64;
      #pragma unroll
      for (int half=0; half<2; half++){
        const float2* efp = ef2h + jn + half*32 + g*8;
        #pragma unroll
        for (int k=0;k<4;k++) cc[half*4+k] = *(const float4*)(efp + 2*k);
      }
      wrd = arow[jn>>6];
    }
    #pragma unroll
    for (int half = 0; half < 2; half++){
      union { unsigned u[4]; short8 v; } pv_;
      #pragma unroll
      for (int k = 0; k < 4; k++) pv_.u[k] = pu[half][k];
      #pragma unroll
      for (int ct = 0; ct < 4; ct++){
        int r = ct*16 + lr;
        short8 bfr = *(const short8*)&buf[s&1][r][(((half*4+g)^(lr&7))<<3)];
        acc[ct] = __builtin_amdgcn_mfma_f32_16x16x32_bf16(pv_.v, bfr, acc[ct], 0,0,0);
      }
      accd = __builtin_amdgcn_mfma_f32_16x16x32_bf16(pv_.v, ones, accd, 0,0,0);
    }
    __syncthreads();   // vmcnt drain = stage fence; protects buf reuse
  }
  #undef STAGE

  // ---- epilogue: bf16 O-partials + fp32 D-partials ----
  #pragma unroll
  for (int r=0; r<4; r++){
    int row = i_base + w*16 + g*4 + r;
    size_t pbase = (size_t)((h<<JCLOG)|jc)*Nn + row;
    if (lr == 0) Dpart[pbase] = accd[r];
    #pragma unroll
    for (int ct=0; ct<4; ct++)
      Opart[pbase*64 + ct*16 + lr] = f2bf(acc[ct][r]);
  }
}

// ---- layer-1 finish: combine 2 j-chunks, normalize, ELU -> Hmat ----
__global__ void k_fin1(const unsigned short* __restrict__ Op, const float* __restrict__ Dp,
                       unsigned short* __restrict__ Hmat){
  int t = threadIdx.x;
  int c = t & 63, rr = t >> 6;
  int row = blockIdx.x*4 + rr, h = blockIdx.y;
  size_t b0 = (size_t)(h*2+0)*Nn + row;
  size_t b1 = (size_t)(h*2+1)*Nn + row;
  float o = bf2f(Op[b0*64+c]) + bf2f(Op[b1*64+c]);
  float d = Dp[b0] + Dp[b1];
  float v = o / fmaxf(d, 1e-30f);
  v = v > 0.f ? v : __expf(v) - 1.f;
  Hmat[(size_t)row*O1 + h*64 + c] = f2bf(v);
}

// ---- layer-2 finish: combine 16 j-chunks, normalize, ELU, log_softmax ----
__global__ void k_fin2(const unsigned short* __restrict__ Op, const float* __restrict__ Dp,
                       float* __restrict__ out){
  int w = threadIdx.x>>6, l = threadIdx.x&63;
  int row = blockIdx.x*4 + w;
  float o = 0.f, d = 0.f;
  #pragma unroll
  for (int jc=0; jc<16; jc++){
    o += bf2f(Op[((size_t)jc*Nn + row)*64 + l]);
    d += Dp[(size_t)jc*Nn + row];
  }
  float v = o / fmaxf(d, 1e-30f);
  v = v > 0.f ? v : __expf(v) - 1.f;
  float m = v;
  #pragma unroll
  for (int dd=1; dd<64; dd<<=1) m = fmaxf(m, __shfl_xor(m, dd));
  float s = __expf(v - m);
  #pragma unroll
  for (int dd=1; dd<64; dd<<=1) s += __shfl_xor(s, dd);
  out[(size_t)row*64 + l] = v - (m + __logf(s));
}

extern "C" void kernel_launch(void* const* d_in, const int* in_sizes, int n_in,
                              void* d_out, int out_size, void* d_ws, size_t ws_size,
                              hipStream_t stream){
  const float* x  = (const float*)d_in[0];
  const int* adj  = (const int*)d_in[1];
  const float* W  = (const float*)d_in[2];
  const float* a1 = (const float*)d_in[3];
  const float* a2 = (const float*)d_in[4];
  const float* W2 = (const float*)d_in[5];
  const float* a21= (const float*)d_in[6];
  const float* a22= (const float*)d_in[7];
  float* out = (float*)d_out;
  char* ws = (char*)d_ws;

  size_t off=0;
  unsigned long long* adjw = (unsigned long long*)(ws+off); off += (size_t)Nn*64*8;   // 2MB
  unsigned short* xb   = (unsigned short*)(ws+off); off += (size_t)Nn*FIN*2;          // 4MB
  unsigned short* Wb   = (unsigned short*)(ws+off); off += (size_t)O1*FIN*2;          // .5MB
  unsigned short* W2b  = (unsigned short*)(ws+off); off += (size_t)64*FIN*2;          // 64KB
  unsigned short* whT1 = (unsigned short*)(ws+off); off += (size_t)O1*Nn*2;           // 4MB
  unsigned short* Hmat = (unsigned short*)(ws+off); off += (size_t)Nn*O1*2;           // 4MB
  unsigned short* whT2 = (unsigned short*)(ws+off); off += (size_t)64*Nn*2;           // .5MB
  float2* e1f1a = (float2*)(ws+off); off += (size_t)NH*Nn*8;
  float2* e2f2a = (float2*)(ws+off); off += (size_t)NH*Nn*8;
  float2* e1f1b = (float2*)(ws+off); off += (size_t)Nn*8;
  float2* e2f2b = (float2*)(ws+off); off += (size_t)Nn*8;
  // partials: 16 chunk-slots x Nn x 64 bf16 (8MB) + 16 x Nn fp32 D (256KB)
  // layer-1 uses slots (h*2+jc), layer-2 reuses slots jc (dead after k_fin1)
  unsigned short* Opart = (unsigned short*)(ws+off); off += (size_t)16*Nn*64*2;       // 8MB
  float* Dpart = (float*)(ws+off); off += (size_t)16*Nn*4;                            // 256KB

  k_pack_adj<<<(Nn*(size_t)Nn)/256, 256, 0, stream>>>(adj, adjw);
  k_cvt<<<(Nn*FIN/4+255)/256, 256, 0, stream>>>(x, xb, Nn*FIN);
  k_cvt<<<(O1*FIN/4+255)/256, 256, 0, stream>>>(W, Wb, O1*FIN);
  k_cvt<<<(64*FIN/4+255)/256, 256, 0, stream>>>(W2, W2b, 64*FIN);
  k_gemm3<2,4><<<dim3(Nn/32, O1/64), 512, 0, stream>>>(xb, Wb, whT1, Nn, FIN, O1);
  k_wh12<<<dim3(Nn/256, NH), 256, 0, stream>>>(whT1, a1, a2, e1f1a, e2f2a);
  // layer-1 attention: 64 rowtiles x 2 j-chunks x 8 heads = 1024 blocks
  k_attn6<32, 3, 1><<<(Nn/64)*2*NH, 256, 0, stream>>>(adjw, e1f1a, e2f2a, whT1, Opart, Dpart);
  k_fin1<<<dim3(Nn/4, NH), 256, 0, stream>>>(Opart, Dpart, Hmat);
  k_gemm3<2,8><<<dim3(Nn/32, 1), 1024, 0, stream>>>(Hmat, W2b, whT2, Nn, FIN, 64);
  k_wh12<<<dim3(Nn/256, 1), 256, 0, stream>>>(whT2, a21, a22, e1f1b, e2f2b);
  // layer-2 attention: 64 rowtiles x 16 j-chunks = 1024 blocks
  k_attn6<4, 0, 4><<<(Nn/64)*16, 256, 0, stream>>>(adjw, e1f1b, e2f2b, whT2, Opart, Dpart);
  k_fin2<<<Nn/4, 256, 0, stream>>>(Opart, Dpart, out);
  (void)in_sizes; (void)n_in; (void)out_size; (void)ws_size;
}

// Round 11
// 150.975 us; speedup vs baseline: 1.0792x; 1.0470x over previous
//
#include <hip/hip_runtime.h>

#define Nn 4096
#define FIN 512
#define NH 8
#define O1 512
#define LOG2E 1.44269504088896f

typedef __attribute__((ext_vector_type(8))) short short8;
typedef __attribute__((ext_vector_type(4))) float f32x4;
typedef __attribute__((ext_vector_type(2))) unsigned int u32x2;

__device__ __forceinline__ unsigned short f2bf(float f){
  union{float f; unsigned u;} x; x.f=f;
  unsigned r = x.u + 0x7fffu + ((x.u>>16)&1u);
  return (unsigned short)(r>>16);
}
__device__ __forceinline__ float bf2f(unsigned short b){
  union{unsigned u; float f;} x; x.u=((unsigned)b)<<16;
  return x.f;
}
__device__ __forceinline__ unsigned cvtpk_bf16(float a, float b){
  unsigned r; asm("v_cvt_pk_bf16_f32 %0, %1, %2" : "=v"(r) : "v"(a), "v"(b));
  return r;
}
// async 16B global -> LDS (per-lane global src, wave-uniform LDS base + lane*16)
__device__ __forceinline__ void gload_lds16(const unsigned short* g, unsigned short* l){
  __builtin_amdgcn_global_load_lds(
      (const __attribute__((address_space(1))) unsigned int*)g,
      (__attribute__((address_space(3))) unsigned int*)l, 16, 0, 0);
}

// ---- pack adjacency int32 -> bitmask ----
__global__ void k_pack_adj(const int* __restrict__ adj, unsigned long long* __restrict__ adjw){
  size_t tid = (size_t)blockIdx.x*blockDim.x + threadIdx.x;
  int v = __builtin_nontemporal_load(adj + tid);   // 64MB read-once
  unsigned long long m = __ballot(v>0);
  if((threadIdx.x&63)==0) adjw[tid>>6] = m;
}

// ---- f32 -> bf16 convert ----
__global__ void k_cvt(const float* __restrict__ in, unsigned short* __restrict__ out, int n){
  int i = (blockIdx.x*blockDim.x + threadIdx.x)*4;
  if(i>=n) return;
  float4 v = *(const float4*)(in+i);
  u32x2 pk; pk.x = cvtpk_bf16(v.x, v.y); pk.y = cvtpk_bf16(v.z, v.w);
  *(u32x2*)(out+i) = pk;
}

// ---- K-split GEMM: C^T[o][m] = sum_k A[m][k]*B[o][k] ----
template<int NWC, int KS>
__global__ __launch_bounds__(NWC*KS*64, 2)
void k_gemm3(const unsigned short* __restrict__ A, const unsigned short* __restrict__ B,
             unsigned short* __restrict__ CT, int M, int K, int O){
  int t=threadIdx.x, l=t&63, w=t>>6;
  int wc=w%NWC, ks=w/NWC;
  int m0=blockIdx.x*32, o0=blockIdx.y*(NWC*32);
  int row=l&15, kq=(l>>4)*8, g=l>>4;
  int kw=K/KS;
  const unsigned short* Ab = A + (size_t)(m0+row)*K + ks*kw + kq;
  const unsigned short* Bb = B + (size_t)(o0+wc*32+row)*K + ks*kw + kq;
  f32x4 acc[2][2]={};
  #pragma unroll 2
  for(int k0=0;k0<kw;k0+=32){
    short8 a0=*(const short8*)(Ab+k0);
    short8 a1=*(const short8*)(Ab+(size_t)16*K+k0);
    short8 b0=*(const short8*)(Bb+k0);
    short8 b1=*(const short8*)(Bb+(size_t)16*K+k0);
    acc[0][0]=__builtin_amdgcn_mfma_f32_16x16x32_bf16(a0,b0,acc[0][0],0,0,0);
    acc[0][1]=__builtin_amdgcn_mfma_f32_16x16x32_bf16(a0,b1,acc[0][1],0,0,0);
    acc[1][0]=__builtin_amdgcn_mfma_f32_16x16x32_bf16(a1,b0,acc[1][0],0,0,0);
    acc[1][1]=__builtin_amdgcn_mfma_f32_16x16x32_bf16(a1,b1,acc[1][1],0,0,0);
  }
  __shared__ float red[NWC][KS/2][32][36];
  for(int s=KS/2;s>=1;s>>=1){
    if(ks>=s && ks<2*s){
      #pragma unroll
      for(int mi=0;mi<2;mi++)
      #pragma unroll
      for(int oi=0;oi<2;oi++)
      #pragma unroll
      for(int r=0;r<4;r++)
        red[wc][ks-s][mi*16+g*4+r][oi*18+row]=acc[mi][oi][r];
    }
    __syncthreads();
    if(ks<s){
      #pragma unroll
      for(int mi=0;mi<2;mi++)
      #pragma unroll
      for(int oi=0;oi<2;oi++)
      #pragma unroll
      for(int r=0;r<4;r++)
        acc[mi][oi][r]+=red[wc][ks][mi*16+g*4+r][oi*18+row];
    }
    __syncthreads();
  }
  if(ks==0){
    #pragma unroll
    for(int mi=0;mi<2;mi++)
    #pragma unroll
    for(int oi=0;oi<2;oi++){
      int m=m0+mi*16+g*4;
      int o=o0+wc*32+oi*16+row;
      u32x2 pk;
      pk.x=cvtpk_bf16(acc[mi][oi][0], acc[mi][oi][1]);
      pk.y=cvtpk_bf16(acc[mi][oi][2], acc[mi][oi][3]);
      *(u32x2*)&CT[(size_t)o*M+m] = pk;
    }
  }
}

// ---- per-node score factors: row AoS {E1,F1}; col SoA E2[],F2[] ----
__global__ void k_wh12(const unsigned short* __restrict__ whT,
                       const float* __restrict__ a1, const float* __restrict__ a2,
                       float2* __restrict__ e1f1, float* __restrict__ E2a,
                       float* __restrict__ F2a){
  const int M=Nn;
  int n=blockIdx.x*blockDim.x+threadIdx.x;
  int h=blockIdx.y;
  float s1=0.f,s2=0.f;
  for(int c=0;c<64;c++){
    float v=bf2f(whT[(size_t)(h*64+c)*M+n]);
    s1+=v*a1[h*64+c];
    s2+=v*a2[h*64+c];
  }
  float s1L=s1*LOG2E, s2L=s2*LOG2E;
  float2 r1; r1.x=__builtin_amdgcn_exp2f(s1L); r1.y=__builtin_amdgcn_exp2f(0.2f*s1L);
  e1f1[(size_t)h*M+n]=r1;
  E2a[(size_t)h*M+n]=__builtin_amdgcn_exp2f(s2L);
  F2a[(size_t)h*M+n]=__builtin_amdgcn_exp2f(0.2f*s2L);
}

// ---- fused attention v7: 2 waves x 32 rows (RF=2), SoA E/F, reg headroom ----
// V tile [64][64] double-buffered, XOR-swizzled, async gload_lds staged.
// p_ij = adj_ij ? max(E1_i*E2_j, F1_i*F2_j) : 0.  Denominator via ones-MFMA.
template<int JSTEPS, int LOGH, int JCLOG>
__global__ __launch_bounds__(128, 2)
void k_attn7(const unsigned long long* __restrict__ adjw,
             const float2* __restrict__ e1f1, const float* __restrict__ E2a,
             const float* __restrict__ F2a,
             const unsigned short* __restrict__ whT,
             unsigned short* __restrict__ Opart, float* __restrict__ Dpart){
  const int M = Nn;
  __shared__ unsigned short buf[2][64][64];
  int t = threadIdx.x, l = t & 63, w = t >> 6;     // w in {0,1}
  int lr = l & 15, g = l >> 4;
  int bid = blockIdx.x;
  int h = bid & ((1<<LOGH)-1);          // head in low bits -> pinned per XCD
  int bx = bid >> LOGH;
  int jc = bx & ((1<<JCLOG)-1);
  int rowtile = bx >> JCLOG;
  int i_base = rowtile*64 + w*32;       // this wave's 32 rows
  int jbase = jc * (JSTEPS*64);
  const float* E2h = E2a + (size_t)h*M;
  const float* F2h = F2a + (size_t)h*M;
  const unsigned short* Vb = whT + (size_t)h*64*M;

  float E1[2], F1[2];
  const unsigned long long* arow[2];
  #pragma unroll
  for (int rf=0; rf<2; rf++){
    int i = i_base + rf*16 + lr;
    float2 ef = e1f1[(size_t)h*M + i];
    E1[rf]=ef.x; F1[rf]=ef.y;
    arow[rf] = adjw + (size_t)i*64;
  }

  // staging: wave w stages rows [w*32, w*32+32), 4 instrs of 8 rows each.
  // pre-swizzled source: phys group l&7 holds logical group (l&7)^(row&7)
  const unsigned short* vsrc[4];
  int ldst[4];
  #pragma unroll
  for (int k=0;k<4;k++){
    int rloc = w*32 + k*8 + (l>>3);
    vsrc[k] = Vb + (size_t)rloc*M + jbase + (((l&7)^(rloc&7))<<3);
    ldst[k] = w*32 + k*8;
  }

  short8 ones;
  #pragma unroll
  for (int q=0;q<8;q++) ones[q] = (short)0x3F80;

  f32x4 acc[2][4] = {};
  f32x4 accd[2] = {};

  #define STAGE(nb, s) do{ \
      gload_lds16(vsrc[0] + (size_t)(s)*64, &buf[nb][ldst[0]][0]); \
      gload_lds16(vsrc[1] + (size_t)(s)*64, &buf[nb][ldst[1]][0]); \
      gload_lds16(vsrc[2] + (size_t)(s)*64, &buf[nb][ldst[2]][0]); \
      gload_lds16(vsrc[3] + (size_t)(s)*64, &buf[nb][ldst[3]][0]); \
    }while(0)

  // prologue: stage step 0, prefetch step-0 scalars
  STAGE(0, 0);
  f32x4 eS[2][2], fS[2][2];
  unsigned long long wrd[2];
  #pragma unroll
  for (int half=0; half<2; half++){
    int j = jbase + half*32 + g*8;
    eS[half][0] = *(const f32x4*)(E2h + j);
    eS[half][1] = *(const f32x4*)(E2h + j + 4);
    fS[half][0] = *(const f32x4*)(F2h + j);
    fS[half][1] = *(const f32x4*)(F2h + j + 4);
  }
  wrd[0] = arow[0][jbase>>6];
  wrd[1] = arow[1][jbase>>6];
  __syncthreads();   // drains stage(0)

  for (int s = 0; s < JSTEPS; s++){
    if (s+1 < JSTEPS) STAGE((s+1)&1, s+1);   // async, lands during compute
    // ---- P compute: direct subregister indexing, no repack ----
    unsigned pu[2][2][4];
    #pragma unroll
    for (int half = 0; half < 2; half++){
      #pragma unroll
      for (int rf = 0; rf < 2; rf++){
        unsigned bits = (unsigned)(wrd[rf] >> (half*32 + g*8)) & 0xffu;
        float pf[8];
        #pragma unroll
        for (int q = 0; q < 8; q++){
          float Ev = (q<4) ? eS[half][0][q&3] : eS[half][1][q&3];
          float Fv = (q<4) ? fS[half][0][q&3] : fS[half][1][q&3];
          float m = E1[rf]*Ev;
          float f = F1[rf]*Fv;
          float p = fmaxf(m, f);                 // = exp2(LeakyReLU(s))
          int mk = (int)(bits << (31-q)) >> 31;
          pf[q] = __uint_as_float(__float_as_uint(p) & (unsigned)mk);
        }
        #pragma unroll
        for (int k = 0; k < 4; k++) pu[rf][half][k] = cvtpk_bf16(pf[2*k], pf[2*k+1]);
      }
    }
    // ---- prefetch next-step scalars (stay in regs: 256-VGPR budget) ----
    if (s+1 < JSTEPS){
      int jn = jbase + (s+1)*64;
      #pragma unroll
      for (int half=0; half<2; half++){
        int j = jn + half*32 + g*8;
        eS[half][0] = *(const f32x4*)(E2h + j);
        eS[half][1] = *(const f32x4*)(E2h + j + 4);
        fS[half][0] = *(const f32x4*)(F2h + j);
        fS[half][1] = *(const f32x4*)(F2h + j + 4);
      }
      wrd[0] = arow[0][jn>>6];
      wrd[1] = arow[1][jn>>6];
    }
    // ---- MFMA phase: swizzled conflict-free ds_reads, shared by both rf ----
    #pragma unroll
    for (int half = 0; half < 2; half++){
      short8 bfr[4];
      #pragma unroll
      for (int ct = 0; ct < 4; ct++)
        bfr[ct] = *(const short8*)&buf[s&1][ct*16+lr][(((half*4+g)^(lr&7))<<3)];
      #pragma unroll
      for (int rf = 0; rf < 2; rf++){
        union { unsigned u[4]; short8 v; } pv_;
        #pragma unroll
        for (int k = 0; k < 4; k++) pv_.u[k] = pu[rf][half][k];
        #pragma unroll
        for (int ct = 0; ct < 4; ct++)
          acc[rf][ct] = __builtin_amdgcn_mfma_f32_16x16x32_bf16(pv_.v, bfr[ct], acc[rf][ct], 0,0,0);
        accd[rf] = __builtin_amdgcn_mfma_f32_16x16x32_bf16(pv_.v, ones, accd[rf], 0,0,0);
      }
    }
    __syncthreads();   // vmcnt drain = stage fence; protects buf reuse
  }
  #undef STAGE

  // ---- epilogue: bf16 O-partials + fp32 D-partials ----
  #pragma unroll
  for (int rf=0; rf<2; rf++)
  #pragma unroll
  for (int r=0; r<4; r++){
    int row = i_base + rf*16 + g*4 + r;
    size_t pbase = (size_t)((h<<JCLOG)|jc)*Nn + row;
    if (lr == 0) Dpart[pbase] = accd[rf][r];
    #pragma unroll
    for (int ct=0; ct<4; ct++)
      Opart[pbase*64 + ct*16 + lr] = f2bf(acc[rf][ct][r]);
  }
}

// ---- layer-1 finish: combine 2 j-chunks, normalize, ELU -> Hmat ----
__global__ void k_fin1(const unsigned short* __restrict__ Op, const float* __restrict__ Dp,
                       unsigned short* __restrict__ Hmat){
  int t = threadIdx.x;
  int c = t & 63, rr = t >> 6;
  int row = blockIdx.x*4 + rr, h = blockIdx.y;
  size_t b0 = (size_t)(h*2+0)*Nn + row;
  size_t b1 = (size_t)(h*2+1)*Nn + row;
  float o = bf2f(Op[b0*64+c]) + bf2f(Op[b1*64+c]);
  float d = Dp[b0] + Dp[b1];
  float v = o / fmaxf(d, 1e-30f);
  v = v > 0.f ? v : __expf(v) - 1.f;
  Hmat[(size_t)row*O1 + h*64 + c] = f2bf(v);
}

// ---- layer-2 finish: combine 16 j-chunks, normalize, ELU, log_softmax ----
__global__ void k_fin2(const unsigned short* __restrict__ Op, const float* __restrict__ Dp,
                       float* __restrict__ out){
  int w = threadIdx.x>>6, l = threadIdx.x&63;
  int row = blockIdx.x*4 + w;
  float o = 0.f, d = 0.f;
  #pragma unroll
  for (int jc=0; jc<16; jc++){
    o += bf2f(Op[((size_t)jc*Nn + row)*64 + l]);
    d += Dp[(size_t)jc*Nn + row];
  }
  float v = o / fmaxf(d, 1e-30f);
  v = v > 0.f ? v : __expf(v) - 1.f;
  float m = v;
  #pragma unroll
  for (int dd=1; dd<64; dd<<=1) m = fmaxf(m, __shfl_xor(m, dd));
  float s = __expf(v - m);
  #pragma unroll
  for (int dd=1; dd<64; dd<<=1) s += __shfl_xor(s, dd);
  out[(size_t)row*64 + l] = v - (m + __logf(s));
}

extern "C" void kernel_launch(void* const* d_in, const int* in_sizes, int n_in,
                              void* d_out, int out_size, void* d_ws, size_t ws_size,
                              hipStream_t stream){
  const float* x  = (const float*)d_in[0];
  const int* adj  = (const int*)d_in[1];
  const float* W  = (const float*)d_in[2];
  const float* a1 = (const float*)d_in[3];
  const float* a2 = (const float*)d_in[4];
  const float* W2 = (const float*)d_in[5];
  const float* a21= (const float*)d_in[6];
  const float* a22= (const float*)d_in[7];
  float* out = (float*)d_out;
  char* ws = (char*)d_ws;

  size_t off=0;
  unsigned long long* adjw = (unsigned long long*)(ws+off); off += (size_t)Nn*64*8;   // 2MB
  unsigned short* xb   = (unsigned short*)(ws+off); off += (size_t)Nn*FIN*2;          // 4MB
  unsigned short* Wb   = (unsigned short*)(ws+off); off += (size_t)O1*FIN*2;          // .5MB
  unsigned short* W2b  = (unsigned short*)(ws+off); off += (size_t)64*FIN*2;          // 64KB
  unsigned short* whT1 = (unsigned short*)(ws+off); off += (size_t)O1*Nn*2;           // 4MB
  unsigned short* Hmat = (unsigned short*)(ws+off); off += (size_t)Nn*O1*2;           // 4MB
  unsigned short* whT2 = (unsigned short*)(ws+off); off += (size_t)64*Nn*2;           // .5MB
  float2* e1f1a = (float2*)(ws+off); off += (size_t)NH*Nn*8;
  float*  E2aa  = (float*)(ws+off); off += (size_t)NH*Nn*4;
  float*  F2aa  = (float*)(ws+off); off += (size_t)NH*Nn*4;
  float2* e1f1b = (float2*)(ws+off); off += (size_t)Nn*8;
  float*  E2ab  = (float*)(ws+off); off += (size_t)Nn*4;
  float*  F2ab  = (float*)(ws+off); off += (size_t)Nn*4;
  // partials: 16 chunk-slots x Nn x 64 bf16 (8MB) + 16 x Nn fp32 D (256KB)
  unsigned short* Opart = (unsigned short*)(ws+off); off += (size_t)16*Nn*64*2;       // 8MB
  float* Dpart = (float*)(ws+off); off += (size_t)16*Nn*4;                            // 256KB

  k_pack_adj<<<(Nn*(size_t)Nn)/256, 256, 0, stream>>>(adj, adjw);
  k_cvt<<<(Nn*FIN/4+255)/256, 256, 0, stream>>>(x, xb, Nn*FIN);
  k_cvt<<<(O1*FIN/4+255)/256, 256, 0, stream>>>(W, Wb, O1*FIN);
  k_cvt<<<(64*FIN/4+255)/256, 256, 0, stream>>>(W2, W2b, 64*FIN);
  k_gemm3<2,4><<<dim3(Nn/32, O1/64), 512, 0, stream>>>(xb, Wb, whT1, Nn, FIN, O1);
  k_wh12<<<dim3(Nn/256, NH), 256, 0, stream>>>(whT1, a1, a2, e1f1a, E2aa, F2aa);
  // layer-1 attention: 64 rowtiles x 2 j-chunks x 8 heads = 1024 blocks (128 thr)
  k_attn7<32, 3, 1><<<(Nn/64)*2*NH, 128, 0, stream>>>(adjw, e1f1a, E2aa, F2aa, whT1, Opart, Dpart);
  k_fin1<<<dim3(Nn/4, NH), 256, 0, stream>>>(Opart, Dpart, Hmat);
  k_gemm3<2,8><<<dim3(Nn/32, 1), 1024, 0, stream>>>(Hmat, W2b, whT2, Nn, FIN, 64);
  k_wh12<<<dim3(Nn/256, 1), 256, 0, stream>>>(whT2, a21, a22, e1f1b, E2ab, F2ab);
  // layer-2 attention: 64 rowtiles x 16 j-chunks = 1024 blocks (128 thr)
  k_attn7<4, 0, 4><<<(Nn/64)*16, 128, 0, stream>>>(adjw, e1f1b, E2ab, F2ab, whT2, Opart, Dpart);
  k_fin2<<<Nn/4, 256, 0, stream>>>(Opart, Dpart, out);
  (void)in_sizes; (void)n_in; (void)out_size; (void)ws_size;
}